// Round 1
// baseline (573.898 us; speedup 1.0000x reference)
//
#include <hip/hip_runtime.h>
#include <stdint.h>

#define BATCH 512
#define FEAT 512
#define NCLS 100000
#define BM 128
#define BN 128
#define BK 64
#define NBLK_N 782            // ceil(100000/128)
#define NCHUNK (NBLK_N * 2)   // per-row softmax partial chunks (one per 64-col wave tile)
#define SCALE_S 32.0f
#define MARGIN 0.5f
#define MM_CONST 0.23971276930210156f  // 0.5*sin(pi-0.5)
#define PI_F 3.14159265358979f

typedef unsigned int u32;
typedef unsigned short u16;
typedef __bf16 bf16x8 __attribute__((ext_vector_type(8)));
typedef float f32x4 __attribute__((ext_vector_type(4)));

__device__ __forceinline__ u16 f2bf(float f) {
  u32 u = __float_as_uint(f);
  u += 0x7fffu + ((u >> 16) & 1u);
  return (u16)(u >> 16);
}

__device__ __forceinline__ void async_copy16(const void* g, void* l) {
  __builtin_amdgcn_global_load_lds((const __attribute__((address_space(1))) u32*)g,
                                   (__attribute__((address_space(3))) u32*)l,
                                   16, 0, 0);
}

__device__ __forceinline__ float block_reduce_sum(float v, float* sbuf) {
  for (int off = 1; off < 64; off <<= 1) v += __shfl_xor(v, off, 64);
  int wid = threadIdx.x >> 6, lane = threadIdx.x & 63;
  __syncthreads();
  if (lane == 0) sbuf[wid] = v;
  __syncthreads();
  return sbuf[0] + sbuf[1] + sbuf[2] + sbuf[3];
}

// L2-normalize each row of src [nrows x 512] f32 -> bf16 dst
__global__ __launch_bounds__(256) void norm_rows_kernel(const float* __restrict__ src,
                                                        u16* __restrict__ dst) {
  __shared__ float sbuf[4];
  int row = blockIdx.x;
  const float2* p = (const float2*)(src + (size_t)row * FEAT);
  float2 v = p[threadIdx.x];
  float ss = block_reduce_sum(v.x * v.x + v.y * v.y, sbuf);
  float inv = 1.0f / fmaxf(sqrtf(ss), 1e-12f);
  u16 a = f2bf(v.x * inv), b = f2bf(v.y * inv);
  ((u32*)(dst + (size_t)row * FEAT))[threadIdx.x] = (u32)a | ((u32)b << 16);
}

// C[512 x 100000] = Ahat @ Bhat^T (bf16 MFMA), fused clip/margin/scale epilogue,
// writes outs and per-(row, 64-col-chunk) online-softmax partials (max, sumexp).
__global__ __launch_bounds__(256) void gemm_kernel(const u16* __restrict__ A,
                                                   const u16* __restrict__ B,
                                                   const int* __restrict__ labels,
                                                   float* __restrict__ outs,
                                                   float* __restrict__ partials) {
  __shared__ __align__(16) u16 sA[BM * BK];
  __shared__ __align__(16) u16 sB[BN * BK];
  __shared__ int sLab[BM];

  const int tid = threadIdx.x;
  const int lane = tid & 63;
  const int wid = tid >> 6;
  const int waveM = wid >> 1, waveN = wid & 1;
  const int bn = blockIdx.x, bm = blockIdx.y;
  const int quad = lane >> 4, l15 = lane & 15;

  if (tid < BM) sLab[tid] = labels[bm * BM + tid];

  // staging map: LDS 16B-block index idx16 holds global (row=idx16>>3, colblock=(idx16&7)^(row&7))
  int srow[4], scb[4];
#pragma unroll
  for (int rd = 0; rd < 4; ++rd) {
    int idx = rd * 256 + tid;
    int r = idx >> 3;
    srow[rd] = r;
    scb[rd] = (idx & 7) ^ (r & 7);
  }

  f32x4 acc[4][4] = {};

  for (int kt = 0; kt < FEAT / BK; ++kt) {
#pragma unroll
    for (int rd = 0; rd < 4; ++rd) {
      int r = srow[rd], cb = scb[rd];
      const u16* ga = A + (size_t)(bm * BM + r) * FEAT + kt * BK + cb * 8;
      int brow = bn * BN + r;
      if (brow >= NCLS) brow = NCLS - 1;  // clamp; masked in epilogue
      const u16* gb = B + (size_t)brow * FEAT + kt * BK + cb * 8;
      int li = (rd * 256 + tid) * 8;
      async_copy16(ga, &sA[li]);
      async_copy16(gb, &sB[li]);
    }
    __syncthreads();
#pragma unroll
    for (int ks = 0; ks < 2; ++ks) {
      int j0 = ks * 4 + quad;
      bf16x8 aF[4], bF[4];
#pragma unroll
      for (int mi = 0; mi < 4; ++mi) {
        int r = waveM * 64 + mi * 16 + l15;
        aF[mi] = *(const bf16x8*)&sA[(r * 8 + (j0 ^ (r & 7))) * 8];
      }
#pragma unroll
      for (int ni = 0; ni < 4; ++ni) {
        int r = waveN * 64 + ni * 16 + l15;
        bF[ni] = *(const bf16x8*)&sB[(r * 8 + (j0 ^ (r & 7))) * 8];
      }
#pragma unroll
      for (int mi = 0; mi < 4; ++mi)
#pragma unroll
        for (int ni = 0; ni < 4; ++ni)
          acc[mi][ni] = __builtin_amdgcn_mfma_f32_16x16x32_bf16(aF[mi], bF[ni],
                                                                acc[mi][ni], 0, 0, 0);
    }
    __syncthreads();
  }

  // epilogue: clip, margin at label col, scale, store, softmax partials
#pragma unroll
  for (int mi = 0; mi < 4; ++mi) {
#pragma unroll
    for (int reg = 0; reg < 4; ++reg) {
      int rloc = waveM * 64 + mi * 16 + quad * 4 + reg;
      int rg = bm * BM + rloc;
      int lab = sLab[rloc];
      float vals[4];
      float rmax = -1e30f;
#pragma unroll
      for (int ni = 0; ni < 4; ++ni) {
        int cg = bn * BN + waveN * 64 + ni * 16 + l15;
        float v = acc[mi][ni][reg];
        v = fminf(fmaxf(v, -1.0f + 1e-6f), 1.0f - 1e-6f);
        if (cg == lab) {  // cos(arccos(x))==x elsewhere; only label col needs transcendentals
          float th = acosf(v) + MARGIN;
          v = (th < PI_F) ? cosf(th) : (v - MM_CONST);
        }
        v *= SCALE_S;
        if (cg < NCLS)
          outs[(size_t)rg * NCLS + cg] = v;
        else
          v = -1e30f;  // OOB logit: vanishes in online-softmax combine
        vals[ni] = v;
        rmax = fmaxf(rmax, v);
      }
#pragma unroll
      for (int off = 1; off < 16; off <<= 1) rmax = fmaxf(rmax, __shfl_xor(rmax, off, 64));
      float rsum = 0.f;
#pragma unroll
      for (int ni = 0; ni < 4; ++ni) rsum += __expf(vals[ni] - rmax);
#pragma unroll
      for (int off = 1; off < 16; off <<= 1) rsum += __shfl_xor(rsum, off, 64);
      if (l15 == 0) {
        float* p = partials + ((size_t)rg * NCHUNK + (bn * 2 + waveN)) * 2;
        p[0] = rmax;
        p[1] = rsum;
      }
    }
  }
}

// per-row: merge NCHUNK (max,sumexp) partials -> lse; loss_r = lse - outs[r, label[r]]
__global__ __launch_bounds__(256) void combine_kernel(const float* __restrict__ partials,
                                                      const float* __restrict__ outs,
                                                      const int* __restrict__ labels,
                                                      float* __restrict__ loss_r) {
  int r = blockIdx.x, tid = threadIdx.x;
  const float* p = partials + (size_t)r * NCHUNK * 2;
  float m = -1e30f, l = 0.f;
  for (int i = tid; i < NCHUNK; i += 256) {
    float mi = p[2 * i], li = p[2 * i + 1];
    if (mi > m) { l = l * __expf(m - mi) + li; m = mi; }
    else l += li * __expf(mi - m);
  }
  for (int off = 1; off < 64; off <<= 1) {
    float mo = __shfl_xor(m, off, 64);
    float lo = __shfl_xor(l, off, 64);
    if (mo > m) { l = l * __expf(m - mo) + lo; m = mo; }
    else l += lo * __expf(mo - m);
  }
  __shared__ float sm[4], sl[4];
  int wv = tid >> 6, lane = tid & 63;
  if (lane == 0) { sm[wv] = m; sl[wv] = l; }
  __syncthreads();
  if (tid == 0) {
    for (int w = 1; w < 4; ++w) {
      float mo = sm[w], lo = sl[w];
      if (mo > m) { l = l * __expf(m - mo) + lo; m = mo; }
      else l += lo * __expf(mo - m);
    }
    float lse = m + logf(l);
    loss_r[r] = lse - outs[(size_t)r * NCLS + labels[r]];
  }
}

__global__ __launch_bounds__(256) void loss_kernel(const float* __restrict__ loss_r,
                                                   float* __restrict__ out0) {
  __shared__ float sbuf[4];
  float v = loss_r[threadIdx.x] + loss_r[threadIdx.x + 256];
  float s = block_reduce_sum(v, sbuf);
  if (threadIdx.x == 0) out0[0] = s * (1.0f / BATCH);
}

// exact f32 recompute of target_cos_in / target_theta_in / target_cos_out
__global__ __launch_bounds__(256) void targets_kernel(const float* __restrict__ inputs,
                                                      const int* __restrict__ labels,
                                                      const float* __restrict__ weight,
                                                      float* __restrict__ tdst) {
  __shared__ float sbuf[4];
  int r = blockIdx.x, t = threadIdx.x;
  int lab = labels[r];
  const float2* px = (const float2*)(inputs + (size_t)r * FEAT);
  const float2* pw = (const float2*)(weight + (size_t)lab * FEAT);
  float2 x = px[t], w = pw[t];
  float dot = block_reduce_sum(x.x * w.x + x.y * w.y, sbuf);
  float sx = block_reduce_sum(x.x * x.x + x.y * x.y, sbuf);
  float sw = block_reduce_sum(w.x * w.x + w.y * w.y, sbuf);
  if (t == 0) {
    float inv = 1.0f / (fmaxf(sqrtf(sx), 1e-12f) * fmaxf(sqrtf(sw), 1e-12f));
    float ci = fminf(fmaxf(dot * inv, -1.0f + 1e-6f), 1.0f - 1e-6f);
    float th = acosf(ci);
    float t2 = th + MARGIN;
    float co = (t2 < PI_F) ? cosf(t2) : (ci - MM_CONST);
    tdst[r] = ci;
    tdst[BATCH + r] = th;
    tdst[2 * BATCH + r] = co;
  }
}

extern "C" void kernel_launch(void* const* d_in, const int* in_sizes, int n_in,
                              void* d_out, int out_size, void* d_ws, size_t ws_size,
                              hipStream_t stream) {
  const float* inputs = (const float*)d_in[0];
  const int* labels = (const int*)d_in[1];
  const float* weight = (const float*)d_in[2];
  float* out = (float*)d_out;
  float* outs = out + 1;                                // [512][100000]
  float* tdst = out + 1 + (size_t)BATCH * NCLS;         // 3 x [512]

  // workspace layout (~104.3 MiB total)
  char* ws = (char*)d_ws;
  u16* wsA = (u16*)ws;                                  // 512*512*2      = 524288 B
  u16* wsB = (u16*)(ws + 524288);                       // 100000*512*2   = 102400000 B
  float* partials = (float*)(ws + 524288 + 102400000);  // 512*1564*2*4   = 6406144 B
  float* loss_r = (float*)(ws + 524288 + 102400000 + (size_t)BATCH * NCHUNK * 2 * 4);

  norm_rows_kernel<<<BATCH, 256, 0, stream>>>(inputs, wsA);
  norm_rows_kernel<<<NCLS, 256, 0, stream>>>(weight, wsB);
  gemm_kernel<<<dim3(NBLK_N, BATCH / BM), 256, 0, stream>>>(wsA, wsB, labels, outs, partials);
  combine_kernel<<<BATCH, 256, 0, stream>>>(partials, outs, labels, loss_r);
  loss_kernel<<<1, 256, 0, stream>>>(loss_r, out);
  targets_kernel<<<BATCH, 256, 0, stream>>>(inputs, labels, weight, tdst);
}